// Round 3
// baseline (454.747 us; speedup 1.0000x reference)
//
#include <hip/hip_runtime.h>

#define MDIM 512
#define LCH  31
#define CDIM 542   // MD + L - 1
#define INW  1024
#define TN   64            // output n-columns per block
#define NCOL 130           // staged input cols = 2*TN + 2
#define TILE_ELEMS (NCOL*LCH)   // 4030

// ws layout (floats): Xm[m][l][n], yn[m][c], scl_u[2] (monotone-mapped maxima)
#define XM_OFF  0
#define YN_OFF  (MDIM*LCH*MDIM)
#define SCL_OFF (YN_OFF + MDIM*CDIM)

// Monotone map: float -> uint preserving order (for deterministic atomicMax).
static __device__ __forceinline__ unsigned fmap(float f) {
    unsigned b = __float_as_uint(f);
    return (b & 0x80000000u) ? ~b : (b | 0x80000000u);
}
static __device__ __forceinline__ float funmap(unsigned u) {
    return __uint_as_float((u & 0x80000000u) ? (u ^ 0x80000000u) : ~u);
}

// K1: fused bilinear-resize (vertical -> LDS -> l-conv -> horizontal) + H-mult.
// Block = (m, n-tile of 64). All global loads/stores coalesced contiguous spans.
__global__ __launch_bounds__(256) void k1_fused(const float* __restrict__ X,
                                                const float* __restrict__ H,
                                                float* __restrict__ Xm,
                                                unsigned* __restrict__ scl_u) {
    __shared__ float xv[TILE_ELEMS];   // vertically-resized tile [col][l]
    __shared__ float cv[TILE_ELEMS];   // + spectral conv along l

    if (blockIdx.x == 0 && threadIdx.x < 2) scl_u[threadIdx.x] = 0u;  // init maxima

    const int m     = blockIdx.x >> 3;   // bid = m*8 + ntile: pins n-stripe to XCD lane
    const int ntile = blockIdx.x & 7;
    const int n0    = ntile * TN;
    const int g0    = 2*n0 - 1;          // global input col of local col 0

    // vertical 4-tap weights, renormalized at edges (JAX antialias bilinear /2)
    float wy0=0.125f, wy1=0.375f, wy2=0.375f, wy3=0.125f;
    if (m == 0)        wy0 = 0.f;
    if (m == MDIM-1)   wy3 = 0.f;
    if (m == 0 || m == MDIM-1) {
        const float inv = 1.0f/0.875f;
        wy0*=inv; wy1*=inv; wy2*=inv; wy3*=inv;
    }
    const int rr0 = 2*m - 1;
    const size_t RS = (size_t)INW*LCH;   // floats per input row = 31744
    const float* xr0 = X + (size_t)min(max(rr0+0,0),INW-1)*RS;
    const float* xr1 = X + (size_t)(rr0+1)*RS;  // 2m   in [0,1022] always valid
    const float* xr2 = X + (size_t)(rr0+2)*RS;  // 2m+1 in [1,1023] always valid
    const float* xr3 = X + (size_t)min(max(rr0+3,0),INW-1)*RS;

    // phase 1: vertical resize; contiguous coalesced loads (col*31+l flat)
    const int qbase = g0*LCH;
    for (int idx = threadIdx.x; idx < TILE_ELEMS; idx += 256) {
        const int q = qbase + idx;       // offset within a row (floats)
        float a = 0.f;
        if (q >= 0 && q < (int)RS) {
            a = wy0*xr0[q];
            a = fmaf(wy1, xr1[q], a);
            a = fmaf(wy2, xr2[q], a);
            a = fmaf(wy3, xr3[q], a);
        }
        xv[idx] = a;                     // out-of-range cols -> 0 (wx renorm handles)
    }
    __syncthreads();

    // phase 2: spectral conv along l (zero-padded)
    for (int idx = threadIdx.x; idx < TILE_ELEMS; idx += 256) {
        const int l = idx % LCH;
        float c = 0.5f*xv[idx];
        if (l > 0)      c += 0.25f*xv[idx-1];
        if (l < LCH-1)  c += 0.25f*xv[idx+1];
        cv[idx] = c;
    }
    __syncthreads();

    // phase 3: horizontal resize + H multiply; stores coalesced along n
    const float* Hrow = H + ((size_t)m*MDIM + n0)*LCH;
    float* Xrow = Xm + (size_t)m*LCH*MDIM + n0;
    for (int idx = threadIdx.x; idx < LCH*TN; idx += 256) {
        const int l  = idx >> 6;         // /TN
        const int nl = idx & (TN-1);
        const int n  = n0 + nl;
        float wx0=0.125f, wx1=0.375f, wx2=0.375f, wx3=0.125f;
        if (n == 0)        wx0 = 0.f;
        if (n == MDIM-1)   wx3 = 0.f;
        if (n == 0 || n == MDIM-1) {
            const float inv = 1.0f/0.875f;
            wx0*=inv; wx1*=inv; wx2*=inv; wx3*=inv;
        }
        const float* c0 = cv + 2*nl*LCH + l;   // local taps 2nl..2nl+3
        float v = wx0*c0[0];
        v = fmaf(wx1, c0[LCH],   v);
        v = fmaf(wx2, c0[2*LCH], v);
        v = fmaf(wx3, c0[3*LCH], v);
        Xrow[(size_t)l*MDIM + nl] = v * Hrow[nl*LCH + l];
    }
}

// K2: yn[m,c] = sum_i Xm[m][i][c-i]; block max -> atomicMax (deterministic).
__global__ __launch_bounds__(256) void k2_shiftsum(const float* __restrict__ Xm,
                                                   float* __restrict__ yn,
                                                   unsigned* __restrict__ scl_u) {
    const int m = blockIdx.x;
    const float* base = Xm + (size_t)m*LCH*MDIM;
    float lmax = 0.f;                    // yn >= 0
    for (int c = threadIdx.x; c < CDIM; c += 256) {
        float s = 0.f;
        const int ilo = max(0, c - (MDIM-1));
        const int ihi = min(LCH-1, c);
        for (int i = ilo; i <= ihi; ++i)
            s += base[(size_t)i*MDIM + (c - i)];
        yn[m*CDIM + c] = s;
        lmax = fmaxf(lmax, s);
    }
    __shared__ float red[256];
    red[threadIdx.x] = lmax; __syncthreads();
    for (int s = 128; s > 0; s >>= 1) {
        if ((int)threadIdx.x < s)
            red[threadIdx.x] = fmaxf(red[threadIdx.x], red[threadIdx.x+s]);
        __syncthreads();
    }
    if (threadIdx.x == 0) atomicMax(scl_u + 0, fmap(red[0]));
}

// K3: t = H * conv_i(yn/My - y gathered at c=n+i); write out; blockmax -> atomicMax.
__global__ __launch_bounds__(256) void k3_grad(const float* __restrict__ yn,
                                               const float* __restrict__ y,
                                               const float* __restrict__ H,
                                               unsigned* __restrict__ scl_u,
                                               float* __restrict__ out) {
    const int tid  = blockIdx.x * blockDim.x + threadIdx.x;
    const int i    = tid % LCH;
    const int rest = tid / LCH;
    const int n    = rest & (MDIM-1);
    const int m    = rest >> 9;
    const float inv = 1.0f / funmap(scl_u[0]);
    const int c = n + i;
    const float* ynr = yn + (size_t)m*CDIM;
    const float* yr  = y  + (size_t)m*CDIM;
    float v = 0.5f * (ynr[c]*inv - yr[c]);
    if (i > 0)     v += 0.25f*(ynr[c-1]*inv - yr[c-1]);
    if (i < LCH-1) v += 0.25f*(ynr[c+1]*inv - yr[c+1]);
    const float t = H[tid]*v;
    out[tid] = t;
    __shared__ float red[256];
    red[threadIdx.x] = t; __syncthreads();
    for (int s = 128; s > 0; s >>= 1) {
        if ((int)threadIdx.x < s)
            red[threadIdx.x] = fmaxf(red[threadIdx.x], red[threadIdx.x+s]);
        __syncthreads();
    }
    if (threadIdx.x == 0) atomicMax(scl_u + 1, fmap(red[0]));
}

// K4: scale by 1/max, float4 vectorized grid-stride.
__global__ __launch_bounds__(256) void k4_scale(float* __restrict__ out,
                                                const unsigned* __restrict__ scl_u) {
    const float inv = 1.0f / funmap(scl_u[1]);
    float4* o4 = (float4*)out;
    const int n4 = (MDIM*MDIM*LCH)/4;   // 2031616
    for (int idx = blockIdx.x*blockDim.x + threadIdx.x; idx < n4;
         idx += gridDim.x*blockDim.x) {
        float4 v = o4[idx];
        v.x*=inv; v.y*=inv; v.z*=inv; v.w*=inv;
        o4[idx] = v;
    }
}

extern "C" void kernel_launch(void* const* d_in, const int* in_sizes, int n_in,
                              void* d_out, int out_size, void* d_ws, size_t ws_size,
                              hipStream_t stream) {
    const float* X = (const float*)d_in[0];
    const float* y = (const float*)d_in[1];
    const float* H = (const float*)d_in[2];
    float* out = (float*)d_out;
    float* ws  = (float*)d_ws;

    float*    Xm    = ws + XM_OFF;
    float*    yn    = ws + YN_OFF;
    unsigned* scl_u = (unsigned*)(ws + SCL_OFF);

    k1_fused<<<MDIM*8, 256, 0, stream>>>(X, H, Xm, scl_u);            // 4096 blocks
    k2_shiftsum<<<MDIM, 256, 0, stream>>>(Xm, yn, scl_u);             // 512 blocks
    k3_grad<<<(MDIM*MDIM*LCH)/256, 256, 0, stream>>>(yn, y, H, scl_u, out);
    k4_scale<<<2048, 256, 0, stream>>>(out, scl_u);
}

// Round 4
// 122.971 us; speedup vs baseline: 3.6980x; 3.6980x over previous
//
#include <hip/hip_runtime.h>

#define MDIM 512
#define LCH  31
#define CDIM 542   // MD + L - 1
#define INW  1024
#define TN   64            // output n-columns per block (k1)
#define NCOL 130           // staged input cols = 2*TN + 2
#define TILE_ELEMS (NCOL*LCH)   // 4030
#define NELEM (MDIM*MDIM*LCH)   // 8126464
#define GB3  2048               // k3/k4 grid blocks

// ws layout (floats): Xm[m][l][n], yn[m][c], pmaxY[512], pmaxT[2048], scl[2]
#define XM_OFF  0
#define YN_OFF  (MDIM*LCH*MDIM)
#define PMY_OFF (YN_OFF + MDIM*CDIM)
#define PMT_OFF (PMY_OFF + MDIM)
#define SCL_OFF (PMT_OFF + GB3)

// K1: fused bilinear-resize (vertical -> LDS -> l-conv -> horizontal) + H-mult.
// Block = (m, n-tile of 64). All global loads/stores coalesced contiguous spans.
__global__ __launch_bounds__(256) void k1_fused(const float* __restrict__ X,
                                                const float* __restrict__ H,
                                                float* __restrict__ Xm) {
    __shared__ float xv[TILE_ELEMS];   // vertically-resized tile [col][l]
    __shared__ float cv[TILE_ELEMS];   // + spectral conv along l

    const int m     = blockIdx.x >> 3;   // bid = m*8 + ntile
    const int ntile = blockIdx.x & 7;
    const int n0    = ntile * TN;
    const int g0    = 2*n0 - 1;          // global input col of local col 0

    float wy0=0.125f, wy1=0.375f, wy2=0.375f, wy3=0.125f;
    if (m == 0)        wy0 = 0.f;
    if (m == MDIM-1)   wy3 = 0.f;
    if (m == 0 || m == MDIM-1) {
        const float inv = 1.0f/0.875f;
        wy0*=inv; wy1*=inv; wy2*=inv; wy3*=inv;
    }
    const int rr0 = 2*m - 1;
    const size_t RS = (size_t)INW*LCH;   // floats per input row = 31744
    const float* xr0 = X + (size_t)min(max(rr0+0,0),INW-1)*RS;
    const float* xr1 = X + (size_t)(rr0+1)*RS;
    const float* xr2 = X + (size_t)(rr0+2)*RS;
    const float* xr3 = X + (size_t)min(max(rr0+3,0),INW-1)*RS;

    // phase 1: vertical resize; contiguous coalesced loads (col*31+l flat)
    const int qbase = g0*LCH;
    for (int idx = threadIdx.x; idx < TILE_ELEMS; idx += 256) {
        const int q = qbase + idx;
        float a = 0.f;
        if (q >= 0 && q < (int)RS) {
            a = wy0*xr0[q];
            a = fmaf(wy1, xr1[q], a);
            a = fmaf(wy2, xr2[q], a);
            a = fmaf(wy3, xr3[q], a);
        }
        xv[idx] = a;
    }
    __syncthreads();

    // phase 2: spectral conv along l (zero-padded)
    for (int idx = threadIdx.x; idx < TILE_ELEMS; idx += 256) {
        const int l = idx % LCH;
        float c = 0.5f*xv[idx];
        if (l > 0)      c += 0.25f*xv[idx-1];
        if (l < LCH-1)  c += 0.25f*xv[idx+1];
        cv[idx] = c;
    }
    __syncthreads();

    // phase 3: horizontal resize + H multiply; stores coalesced along n
    const float* Hrow = H + ((size_t)m*MDIM + n0)*LCH;
    float* Xrow = Xm + (size_t)m*LCH*MDIM + n0;
    for (int idx = threadIdx.x; idx < LCH*TN; idx += 256) {
        const int l  = idx >> 6;
        const int nl = idx & (TN-1);
        const int n  = n0 + nl;
        float wx0=0.125f, wx1=0.375f, wx2=0.375f, wx3=0.125f;
        if (n == 0)        wx0 = 0.f;
        if (n == MDIM-1)   wx3 = 0.f;
        if (n == 0 || n == MDIM-1) {
            const float inv = 1.0f/0.875f;
            wx0*=inv; wx1*=inv; wx2*=inv; wx3*=inv;
        }
        const float* c0 = cv + 2*nl*LCH + l;
        float v = wx0*c0[0];
        v = fmaf(wx1, c0[LCH],   v);
        v = fmaf(wx2, c0[2*LCH], v);
        v = fmaf(wx3, c0[3*LCH], v);
        Xrow[(size_t)l*MDIM + nl] = v * Hrow[nl*LCH + l];
    }
}

// K2: yn[m,c] = sum_i Xm[m][i][c-i]; per-row max -> pmaxY[m] (plain store).
__global__ __launch_bounds__(256) void k2_shiftsum(const float* __restrict__ Xm,
                                                   float* __restrict__ yn,
                                                   float* __restrict__ pmaxY) {
    const int m = blockIdx.x;
    const float* base = Xm + (size_t)m*LCH*MDIM;
    float lmax = -3.4e38f;
    for (int c = threadIdx.x; c < CDIM; c += 256) {
        float s = 0.f;
        const int ilo = max(0, c - (MDIM-1));
        const int ihi = min(LCH-1, c);
        for (int i = ilo; i <= ihi; ++i)
            s += base[(size_t)i*MDIM + (c - i)];
        yn[m*CDIM + c] = s;
        lmax = fmaxf(lmax, s);
    }
    __shared__ float red[256];
    red[threadIdx.x] = lmax; __syncthreads();
    for (int s = 128; s > 0; s >>= 1) {
        if ((int)threadIdx.x < s)
            red[threadIdx.x] = fmaxf(red[threadIdx.x], red[threadIdx.x+s]);
        __syncthreads();
    }
    if (threadIdx.x == 0) pmaxY[m] = red[0];
}

// Reduce n partial maxes -> out_inv[0] = 1/max. Single block, deterministic.
__global__ __launch_bounds__(256) void kmax_reduce(const float* __restrict__ pmax,
                                                   int n,
                                                   float* __restrict__ out_inv) {
    __shared__ float red[256];
    float lmax = -3.4e38f;
    for (int i = threadIdx.x; i < n; i += 256)
        lmax = fmaxf(lmax, pmax[i]);
    red[threadIdx.x] = lmax; __syncthreads();
    for (int s = 128; s > 0; s >>= 1) {
        if ((int)threadIdx.x < s)
            red[threadIdx.x] = fmaxf(red[threadIdx.x], red[threadIdx.x+s]);
        __syncthreads();
    }
    if (threadIdx.x == 0) out_inv[0] = 1.0f / red[0];
}

// t(idx) = H[idx] * conv_i(yn/My - y at c=n+i)  -- shared by k3 (max) and k4 (write)
__device__ __forceinline__ float t_elem(int idx,
                                        const float* __restrict__ yn,
                                        const float* __restrict__ y,
                                        const float* __restrict__ H,
                                        float inv) {
    const int i    = idx % LCH;
    const int rest = idx / LCH;
    const int n    = rest & (MDIM-1);
    const int m    = rest >> 9;
    const int c    = n + i;
    const float* ynr = yn + (size_t)m*CDIM;
    const float* yr  = y  + (size_t)m*CDIM;
    float v = 0.5f * (ynr[c]*inv - yr[c]);
    if (i > 0)     v += 0.25f*(ynr[c-1]*inv - yr[c-1]);
    if (i < LCH-1) v += 0.25f*(ynr[c+1]*inv - yr[c+1]);
    return H[idx]*v;
}

// K3: block-max of t over grid-stride range -> pmaxT[bid]. No stores of t.
__global__ __launch_bounds__(256) void k3_max(const float* __restrict__ yn,
                                              const float* __restrict__ y,
                                              const float* __restrict__ H,
                                              const float* __restrict__ scl,
                                              float* __restrict__ pmaxT) {
    const float inv = scl[0];
    float lmax = -3.4e38f;
    for (int idx = blockIdx.x*blockDim.x + threadIdx.x; idx < NELEM;
         idx += GB3*256)
        lmax = fmaxf(lmax, t_elem(idx, yn, y, H, inv));
    __shared__ float red[256];
    red[threadIdx.x] = lmax; __syncthreads();
    for (int s = 128; s > 0; s >>= 1) {
        if ((int)threadIdx.x < s)
            red[threadIdx.x] = fmaxf(red[threadIdx.x], red[threadIdx.x+s]);
        __syncthreads();
    }
    if (threadIdx.x == 0) pmaxT[blockIdx.x] = red[0];
}

// K4: recompute t, scale by 1/maxT, write out (coalesced, single pass).
__global__ __launch_bounds__(256) void k4_out(const float* __restrict__ yn,
                                              const float* __restrict__ y,
                                              const float* __restrict__ H,
                                              const float* __restrict__ scl,
                                              float* __restrict__ out) {
    const float inv  = scl[0];
    const float invT = scl[1];
    for (int idx = blockIdx.x*blockDim.x + threadIdx.x; idx < NELEM;
         idx += GB3*256)
        out[idx] = t_elem(idx, yn, y, H, inv) * invT;
}

extern "C" void kernel_launch(void* const* d_in, const int* in_sizes, int n_in,
                              void* d_out, int out_size, void* d_ws, size_t ws_size,
                              hipStream_t stream) {
    const float* X = (const float*)d_in[0];
    const float* y = (const float*)d_in[1];
    const float* H = (const float*)d_in[2];
    float* out = (float*)d_out;
    float* ws  = (float*)d_ws;

    float* Xm    = ws + XM_OFF;
    float* yn    = ws + YN_OFF;
    float* pmaxY = ws + PMY_OFF;
    float* pmaxT = ws + PMT_OFF;
    float* scl   = ws + SCL_OFF;   // [0]=1/maxY, [1]=1/maxT

    k1_fused<<<MDIM*8, 256, 0, stream>>>(X, H, Xm);                 // 4096 blocks
    k2_shiftsum<<<MDIM, 256, 0, stream>>>(Xm, yn, pmaxY);           // 512 blocks
    kmax_reduce<<<1, 256, 0, stream>>>(pmaxY, MDIM, scl);
    k3_max<<<GB3, 256, 0, stream>>>(yn, y, H, scl, pmaxT);          // 2048 blocks
    kmax_reduce<<<1, 256, 0, stream>>>(pmaxT, GB3, scl + 1);
    k4_out<<<GB3, 256, 0, stream>>>(yn, y, H, scl, out);
}

// Round 5
// 109.865 us; speedup vs baseline: 4.1392x; 1.1193x over previous
//
#include <hip/hip_runtime.h>

#define MDIM 512
#define LCH  31
#define CDIM 542   // MD + L - 1
#define INW  1024
#define TN   64            // output n-columns per block (k1)
#define NV4  1008          // float4 loads per row slice = 4032 floats
#define NELEM (MDIM*MDIM*LCH)   // 8126464
#define GB3  2048               // k3/k4 grid blocks

// ws layout (floats): Xm[m][l][n], yn[m][c], pmaxY[512], pmaxT[2048], scl[2]
#define XM_OFF  0
#define YN_OFF  (MDIM*LCH*MDIM)
#define PMY_OFF (YN_OFF + MDIM*CDIM)
#define PMT_OFF (PMY_OFF + MDIM)
#define SCL_OFF (PMT_OFF + GB3)

// K1: fused bilinear-resize + l-conv + H-mult.
// Block = (m, n-tile of 64). Phase 1: float4-vectorized vertical 4-tap into LDS.
// Phase 2: l-conv fused into horizontal 4-tap + H multiply. One barrier total.
// LDS tile covers flat q in [qa, qa+4032) where q = col*31 + l within the input
// row; qbase = (2*n0-1)*31 == 1 (mod 4) for every tile -> constant shift of 1.
__global__ __launch_bounds__(256) void k1_fused(const float* __restrict__ X,
                                                const float* __restrict__ H,
                                                float* __restrict__ Xm) {
    __shared__ float xv[NV4*4];        // 16128 B: vertically-resized flat tile

    const int m     = blockIdx.x >> 3;   // bid = m*8 + ntile
    const int ntile = blockIdx.x & 7;
    const int n0    = ntile * TN;

    float wy0=0.125f, wy1=0.375f, wy2=0.375f, wy3=0.125f;
    if (m == 0)        wy0 = 0.f;
    if (m == MDIM-1)   wy3 = 0.f;
    if (m == 0 || m == MDIM-1) {
        const float inv = 1.0f/0.875f;
        wy0*=inv; wy1*=inv; wy2*=inv; wy3*=inv;
    }
    const int rr0 = 2*m - 1;
    const int RS = INW*LCH;              // floats per input row = 31744
    const float* xr0 = X + (size_t)min(max(rr0+0,0),INW-1)*RS;
    const float* xr1 = X + (size_t)(rr0+1)*RS;
    const float* xr2 = X + (size_t)(rr0+2)*RS;
    const float* xr3 = X + (size_t)min(max(rr0+3,0),INW-1)*RS;

    const int qbase = (2*n0 - 1)*LCH;    // ≡ 1 (mod 4)
    const int qa    = qbase - 1;         // float4-aligned start

    // phase 1: vertical resize, float4 loads, b128 LDS writes
    for (int vi = threadIdx.x; vi < NV4; vi += 256) {
        const int q0 = qa + 4*vi;
        float4 a;
        if (q0 >= 0 && q0 + 4 <= RS) {
            const float4 r0 = *(const float4*)(xr0 + q0);
            const float4 r1 = *(const float4*)(xr1 + q0);
            const float4 r2 = *(const float4*)(xr2 + q0);
            const float4 r3 = *(const float4*)(xr3 + q0);
            a.x = fmaf(wy0,r0.x, fmaf(wy1,r1.x, fmaf(wy2,r2.x, wy3*r3.x)));
            a.y = fmaf(wy0,r0.y, fmaf(wy1,r1.y, fmaf(wy2,r2.y, wy3*r3.y)));
            a.z = fmaf(wy0,r0.z, fmaf(wy1,r1.z, fmaf(wy2,r2.z, wy3*r3.z)));
            a.w = fmaf(wy0,r0.w, fmaf(wy1,r1.w, fmaf(wy2,r2.w, wy3*r3.w)));
        } else {
            float t[4];
            #pragma unroll
            for (int e = 0; e < 4; ++e) {
                const int q = q0 + e;
                t[e] = 0.f;
                if (q >= 0 && q < RS)
                    t[e] = fmaf(wy0,xr0[q], fmaf(wy1,xr1[q],
                           fmaf(wy2,xr2[q], wy3*xr3[q])));
            }
            a.x=t[0]; a.y=t[1]; a.z=t[2]; a.w=t[3];
        }
        *(float4*)&xv[4*vi] = a;
    }
    __syncthreads();

    // phase 2: l-conv (in-LDS taps) + horizontal 4-tap + H multiply
    const float* Hrow = H + ((size_t)m*MDIM + n0)*LCH;
    float* Xrow = Xm + (size_t)m*LCH*MDIM + n0;
    for (int idx = threadIdx.x; idx < LCH*TN; idx += 256) {
        const int l  = idx >> 6;         // 0..30
        const int nl = idx & (TN-1);
        const int n  = n0 + nl;
        float wx0=0.125f, wx1=0.375f, wx2=0.375f, wx3=0.125f;
        if (n == 0)        wx0 = 0.f;
        if (n == MDIM-1)   wx3 = 0.f;
        if (n == 0 || n == MDIM-1) {
            const float inv = 1.0f/0.875f;
            wx0*=inv; wx1*=inv; wx2*=inv; wx3*=inv;
        }
        const float wb[4] = {wx0, wx1, wx2, wx3};
        // local flat index for (col=2nl+b, l): (2nl+b)*31 + l + 1 (shift qa->qbase)
        const float* p0 = xv + 2*nl*LCH + l + 1;
        float acc = 0.f;
        #pragma unroll
        for (int b = 0; b < 4; ++b) {
            const float* p = p0 + b*LCH;
            float c = 0.5f*p[0];
            if (l > 0)      c += 0.25f*p[-1];
            if (l < LCH-1)  c += 0.25f*p[1];
            acc = fmaf(wb[b], c, acc);
        }
        Xrow[(size_t)l*MDIM + nl] = acc * Hrow[nl*LCH + l];
    }
}

// K2: yn[m,c] = sum_i Xm[m][i][c-i]; per-row max -> pmaxY[m] (plain store).
__global__ __launch_bounds__(256) void k2_shiftsum(const float* __restrict__ Xm,
                                                   float* __restrict__ yn,
                                                   float* __restrict__ pmaxY) {
    const int m = blockIdx.x;
    const float* base = Xm + (size_t)m*LCH*MDIM;
    float lmax = -3.4e38f;
    for (int c = threadIdx.x; c < CDIM; c += 256) {
        float s = 0.f;
        const int ilo = max(0, c - (MDIM-1));
        const int ihi = min(LCH-1, c);
        for (int i = ilo; i <= ihi; ++i)
            s += base[(size_t)i*MDIM + (c - i)];
        yn[m*CDIM + c] = s;
        lmax = fmaxf(lmax, s);
    }
    __shared__ float red[256];
    red[threadIdx.x] = lmax; __syncthreads();
    for (int s = 128; s > 0; s >>= 1) {
        if ((int)threadIdx.x < s)
            red[threadIdx.x] = fmaxf(red[threadIdx.x], red[threadIdx.x+s]);
        __syncthreads();
    }
    if (threadIdx.x == 0) pmaxY[m] = red[0];
}

// Reduce n partial maxes -> out_inv[0] = 1/max. Single block, deterministic.
__global__ __launch_bounds__(256) void kmax_reduce(const float* __restrict__ pmax,
                                                   int n,
                                                   float* __restrict__ out_inv) {
    __shared__ float red[256];
    float lmax = -3.4e38f;
    for (int i = threadIdx.x; i < n; i += 256)
        lmax = fmaxf(lmax, pmax[i]);
    red[threadIdx.x] = lmax; __syncthreads();
    for (int s = 128; s > 0; s >>= 1) {
        if ((int)threadIdx.x < s)
            red[threadIdx.x] = fmaxf(red[threadIdx.x], red[threadIdx.x+s]);
        __syncthreads();
    }
    if (threadIdx.x == 0) out_inv[0] = 1.0f / red[0];
}

// t(idx) = H[idx] * conv_i(yn/My - y at c=n+i)  -- shared by k3 (max) and k4 (write)
__device__ __forceinline__ float t_elem(int idx,
                                        const float* __restrict__ yn,
                                        const float* __restrict__ y,
                                        const float* __restrict__ H,
                                        float inv) {
    const int i    = idx % LCH;
    const int rest = idx / LCH;
    const int n    = rest & (MDIM-1);
    const int m    = rest >> 9;
    const int c    = n + i;
    const float* ynr = yn + (size_t)m*CDIM;
    const float* yr  = y  + (size_t)m*CDIM;
    float v = 0.5f * (ynr[c]*inv - yr[c]);
    if (i > 0)     v += 0.25f*(ynr[c-1]*inv - yr[c-1]);
    if (i < LCH-1) v += 0.25f*(ynr[c+1]*inv - yr[c+1]);
    return H[idx]*v;
}

// K3: block-max of t over grid-stride range -> pmaxT[bid]. No stores of t.
__global__ __launch_bounds__(256) void k3_max(const float* __restrict__ yn,
                                              const float* __restrict__ y,
                                              const float* __restrict__ H,
                                              const float* __restrict__ scl,
                                              float* __restrict__ pmaxT) {
    const float inv = scl[0];
    float lmax = -3.4e38f;
    for (int idx = blockIdx.x*blockDim.x + threadIdx.x; idx < NELEM;
         idx += GB3*256)
        lmax = fmaxf(lmax, t_elem(idx, yn, y, H, inv));
    __shared__ float red[256];
    red[threadIdx.x] = lmax; __syncthreads();
    for (int s = 128; s > 0; s >>= 1) {
        if ((int)threadIdx.x < s)
            red[threadIdx.x] = fmaxf(red[threadIdx.x], red[threadIdx.x+s]);
        __syncthreads();
    }
    if (threadIdx.x == 0) pmaxT[blockIdx.x] = red[0];
}

// K4: recompute t, scale by 1/maxT, write out (coalesced, single pass).
__global__ __launch_bounds__(256) void k4_out(const float* __restrict__ yn,
                                              const float* __restrict__ y,
                                              const float* __restrict__ H,
                                              const float* __restrict__ scl,
                                              float* __restrict__ out) {
    const float inv  = scl[0];
    const float invT = scl[1];
    for (int idx = blockIdx.x*blockDim.x + threadIdx.x; idx < NELEM;
         idx += GB3*256)
        out[idx] = t_elem(idx, yn, y, H, inv) * invT;
}

extern "C" void kernel_launch(void* const* d_in, const int* in_sizes, int n_in,
                              void* d_out, int out_size, void* d_ws, size_t ws_size,
                              hipStream_t stream) {
    const float* X = (const float*)d_in[0];
    const float* y = (const float*)d_in[1];
    const float* H = (const float*)d_in[2];
    float* out = (float*)d_out;
    float* ws  = (float*)d_ws;

    float* Xm    = ws + XM_OFF;
    float* yn    = ws + YN_OFF;
    float* pmaxY = ws + PMY_OFF;
    float* pmaxT = ws + PMT_OFF;
    float* scl   = ws + SCL_OFF;   // [0]=1/maxY, [1]=1/maxT

    k1_fused<<<MDIM*8, 256, 0, stream>>>(X, H, Xm);                 // 4096 blocks
    k2_shiftsum<<<MDIM, 256, 0, stream>>>(Xm, yn, pmaxY);           // 512 blocks
    kmax_reduce<<<1, 256, 0, stream>>>(pmaxY, MDIM, scl);
    k3_max<<<GB3, 256, 0, stream>>>(yn, y, H, scl, pmaxT);          // 2048 blocks
    kmax_reduce<<<1, 256, 0, stream>>>(pmaxT, GB3, scl + 1);
    k4_out<<<GB3, 256, 0, stream>>>(yn, y, H, scl, out);
}